// Round 1
// baseline (20.895 us; speedup 1.0000x reference)
//
#include <hip/hip_runtime.h>

// KroneckerLinear: out = x @ kron(f1,f2)^T + bias
//   x   [64, 8192] f32      (d_in[0])
//   f1  [128,128]  f32      (d_in[1])
//   f2  [64, 64]   f32      (d_in[2])
//   bias[8192]     f32      (d_in[3])
//   out [64, 8192] f32
//
// Factored: out[b, i1*64+i2] = bias[i1*64+i2]
//         + sum_j1 f1[i1,j1] * ( sum_j2 x[b, j1*64+j2] * f2[i2,j2] )
// K1: T[r=(b*128+j1), i2] = X[r,:] . f2[i2,:]   (T in d_ws, 2MB f32)
// K2: out[b] = f1 @ T[b] + bias

__global__ __launch_bounds__(256) void kron_k1(const float* __restrict__ X,
                                               const float* __restrict__ f2,
                                               float* __restrict__ T) {
    // One block = 16 rows of X[8192][64]; outputs T[16][64], 4 per thread.
    __shared__ float f2t[64 * 65];  // transposed + padded: f2t[j2*65+i2] = f2[i2*64+j2]
    const int t = threadIdx.x;

    // Stage f2 transposed. Coalesced global read; LDS write banks spread by +1 pad.
#pragma unroll
    for (int k = 0; k < 16; ++k) {
        int idx = t + k * 256;           // 0..4095
        int i2s = idx >> 6;              // f2 row
        int j2s = idx & 63;              // f2 col
        f2t[j2s * 65 + i2s] = f2[idx];
    }
    __syncthreads();

    const int i2 = t & 63;               // lane -> output column
    const int rw = t >> 6;               // 0..3 (wave id; wave-uniform)
    const int r0 = blockIdx.x * 16;

    const float4* Xv = reinterpret_cast<const float4*>(X);
    float acc0 = 0.f, acc1 = 0.f, acc2 = 0.f, acc3 = 0.f;

#pragma unroll
    for (int j2c = 0; j2c < 16; ++j2c) {
        // wave-uniform global float4 loads of X rows (L1 broadcast, 1 txn/wave)
        float4 x0 = Xv[(r0 + rw + 0) * 16 + j2c];
        float4 x1 = Xv[(r0 + rw + 4) * 16 + j2c];
        float4 x2 = Xv[(r0 + rw + 8) * 16 + j2c];
        float4 x3 = Xv[(r0 + rw + 12) * 16 + j2c];
        // per-lane LDS reads, (j2+i2)%32 banks -> 2-way (free)
        float fv0 = f2t[(j2c * 4 + 0) * 65 + i2];
        float fv1 = f2t[(j2c * 4 + 1) * 65 + i2];
        float fv2 = f2t[(j2c * 4 + 2) * 65 + i2];
        float fv3 = f2t[(j2c * 4 + 3) * 65 + i2];
        acc0 += x0.x * fv0 + x0.y * fv1 + x0.z * fv2 + x0.w * fv3;
        acc1 += x1.x * fv0 + x1.y * fv1 + x1.z * fv2 + x1.w * fv3;
        acc2 += x2.x * fv0 + x2.y * fv1 + x2.z * fv2 + x2.w * fv3;
        acc3 += x3.x * fv0 + x3.y * fv1 + x3.z * fv2 + x3.w * fv3;
    }

    T[(r0 + rw + 0) * 64 + i2] = acc0;   // 256B coalesced per wave
    T[(r0 + rw + 4) * 64 + i2] = acc1;
    T[(r0 + rw + 8) * 64 + i2] = acc2;
    T[(r0 + rw + 12) * 64 + i2] = acc3;
}

__global__ __launch_bounds__(256) void kron_k2(const float* __restrict__ T,
                                               const float* __restrict__ f1,
                                               const float* __restrict__ bias,
                                               float* __restrict__ out) {
    // block = (b, i1-group of 16): out[b, i1g*16 .. +16, 0..63], 4 outputs/thread.
    __shared__ float Ts[128 * 64];   // 32KB: T[b] full
    __shared__ float f1s[16 * 128];  // 8KB: 16 rows of f1
    const int t = threadIdx.x;
    const int b = blockIdx.x >> 3;
    const int i1g = blockIdx.x & 7;

    // stage T[b]: 2048 float4, 8/thread, coalesced
    const float4* Tv = reinterpret_cast<const float4*>(T + b * 8192);
    float4* Tsv = reinterpret_cast<float4*>(Ts);
#pragma unroll
    for (int k = 0; k < 8; ++k) Tsv[t + k * 256] = Tv[t + k * 256];

    // stage f1 rows [i1g*16, +16): 512 float4, 2/thread, coalesced
    const float4* F1v = reinterpret_cast<const float4*>(f1 + i1g * 16 * 128);
    float4* F1sv = reinterpret_cast<float4*>(f1s);
#pragma unroll
    for (int k = 0; k < 2; ++k) F1sv[t + k * 256] = F1v[t + k * 256];

    __syncthreads();

    const int i2 = t & 63;
    const int rw = t >> 6;  // 0..3, wave-uniform

    float acc0 = 0.f, acc1 = 0.f, acc2 = 0.f, acc3 = 0.f;

#pragma unroll 8
    for (int j1c = 0; j1c < 32; ++j1c) {
        // per-lane LDS: banks = i2%32 -> 2-way (free)
        float tv0 = Ts[(j1c * 4 + 0) * 64 + i2];
        float tv1 = Ts[(j1c * 4 + 1) * 64 + i2];
        float tv2 = Ts[(j1c * 4 + 2) * 64 + i2];
        float tv3 = Ts[(j1c * 4 + 3) * 64 + i2];
        // wave-uniform float4 LDS reads of f1 rows (broadcast)
        const float4 fa = *reinterpret_cast<const float4*>(&f1s[(rw + 0) * 128 + j1c * 4]);
        const float4 fb = *reinterpret_cast<const float4*>(&f1s[(rw + 4) * 128 + j1c * 4]);
        const float4 fc = *reinterpret_cast<const float4*>(&f1s[(rw + 8) * 128 + j1c * 4]);
        const float4 fd = *reinterpret_cast<const float4*>(&f1s[(rw + 12) * 128 + j1c * 4]);
        acc0 += fa.x * tv0 + fa.y * tv1 + fa.z * tv2 + fa.w * tv3;
        acc1 += fb.x * tv0 + fb.y * tv1 + fb.z * tv2 + fb.w * tv3;
        acc2 += fc.x * tv0 + fc.y * tv1 + fc.z * tv2 + fc.w * tv3;
        acc3 += fd.x * tv0 + fd.y * tv1 + fd.z * tv2 + fd.w * tv3;
    }

#pragma unroll
    for (int m = 0; m < 4; ++m) {
        int i1 = i1g * 16 + rw + m * 4;
        int col = i1 * 64 + i2;
        float a = (m == 0) ? acc0 : (m == 1) ? acc1 : (m == 2) ? acc2 : acc3;
        out[b * 8192 + col] = a + bias[col];   // 256B coalesced per wave
    }
}

extern "C" void kernel_launch(void* const* d_in, const int* in_sizes, int n_in,
                              void* d_out, int out_size, void* d_ws, size_t ws_size,
                              hipStream_t stream) {
    const float* x = (const float*)d_in[0];
    const float* f1 = (const float*)d_in[1];
    const float* f2 = (const float*)d_in[2];
    const float* bias = (const float*)d_in[3];
    float* out = (float*)d_out;
    float* T = (float*)d_ws;  // 8192*64 f32 = 2MB scratch

    // K1: T[8192][64] = X[8192][64] @ f2^T   (512 blocks x 16 rows)
    kron_k1<<<512, 256, 0, stream>>>(x, f2, T);
    // K2: out[b] = f1 @ T[b] + bias          (512 blocks = 64 b x 8 i1-groups)
    kron_k2<<<512, 256, 0, stream>>>(T, f1, bias, out);
}

// Round 2
// 12.382 us; speedup vs baseline: 1.6875x; 1.6875x over previous
//
#include <hip/hip_runtime.h>

// KroneckerLinear fused, bf16 MFMA:
//   out[b, i1*64+i2] = bias[i1*64+i2]
//     + sum_j1 f1[i1,j1] * ( sum_j2 x[b, j1*64+j2] * f2[i2,j2] )
//
// Grid = 64 b * 4 i2-quarters (i2' = 16 cols per block) -> T is block-private,
// zero redundant FLOPs. Block = 512 thr = 8 waves; wave w owns j1-tile (phase B)
// and i1-tile (phase C), both 16 rows.
//
// mfma_f32_16x16x32_bf16 layouts (per cdna_hip_programming.md §3, m89-verified C/D):
//   A: lane L holds A[L&15][(L>>4)*8 + i], i=0..7 (8 contiguous K elems)
//   B: lane L holds B[(L>>4)*8 + i][L&15]
//   C/D: lane L reg r -> (row=(L>>4)*4+r, col=L&15)

typedef __attribute__((ext_vector_type(8))) short bf16x8;
typedef __attribute__((ext_vector_type(4))) float f32x4;

static __device__ __forceinline__ unsigned short f2bf(float f) {
    unsigned int u = __builtin_bit_cast(unsigned int, f);
    u += 0x7FFFu + ((u >> 16) & 1u);   // RNE (inputs are finite)
    return (unsigned short)(u >> 16);
}

static __device__ __forceinline__ bf16x8 pack8(float4 a, float4 b) {
    bf16x8 v;
    v[0] = (short)f2bf(a.x); v[1] = (short)f2bf(a.y);
    v[2] = (short)f2bf(a.z); v[3] = (short)f2bf(a.w);
    v[4] = (short)f2bf(b.x); v[5] = (short)f2bf(b.y);
    v[6] = (short)f2bf(b.z); v[7] = (short)f2bf(b.w);
    return v;
}

__global__ __launch_bounds__(512) void kron_fused(const float* __restrict__ x,
                                                  const float* __restrict__ f1,
                                                  const float* __restrict__ f2,
                                                  const float* __restrict__ bias,
                                                  float* __restrict__ out) {
    // Tt[i2'][j1] bf16: 16 rows x 128 cols x 2B = 4KB, rows 256B, XOR-swizzled
    // (byte ^= (i2'&7)<<4) so stride-256B column reads don't bank-conflict.
    __shared__ unsigned int TtU[16 * 64];
    unsigned char* Tt = reinterpret_cast<unsigned char*>(TtU);

    const int t = threadIdx.x;
    const int L = t & 63;
    const int w = t >> 6;              // wave 0..7
    const int b = blockIdx.x >> 2;
    const int q = blockIdx.x & 3;
    const int lm = L & 15;             // tile row (A/M) or col (B/N / C-col)
    const int lk = L >> 4;             // k-group 0..3

    // ---------------- Phase B: T = Xb @ f2q^T (wave's 16 j1 rows) -------------
    const float* xb = x + b * 8192;
    f32x4 acc = {0.f, 0.f, 0.f, 0.f};
#pragma unroll
    for (int c = 0; c < 2; ++c) {      // K chunks of 32 (j2)
        const float4* pa = reinterpret_cast<const float4*>(
            xb + (16 * w + lm) * 64 + 32 * c + lk * 8);
        float4 a0 = pa[0], a1 = pa[1];
        const float4* pb = reinterpret_cast<const float4*>(
            f2 + (16 * q + lm) * 64 + 32 * c + lk * 8);
        float4 b0 = pb[0], b1 = pb[1];
        bf16x8 af = pack8(a0, a1);
        bf16x8 bf = pack8(b0, b1);
        acc = __builtin_amdgcn_mfma_f32_16x16x32_bf16(af, bf, acc, 0, 0, 0);
    }

    // acc reg r = T[j1 = 16w + lk*4 + r][i2' = lm]; store transposed as bf16:
    // Tt[lm][16w + lk*4 .. +4] = 8B contiguous, swizzled.
    {
        unsigned int lo = ((unsigned)f2bf(acc[1]) << 16) | f2bf(acc[0]);
        unsigned int hi = ((unsigned)f2bf(acc[3]) << 16) | f2bf(acc[2]);
        unsigned int byte = (unsigned)(lm * 256 + (16 * w + lk * 4) * 2);
        byte ^= (unsigned)((lm & 7) << 4);
        *reinterpret_cast<uint2*>(&Tt[byte]) = make_uint2(lo, hi);
    }
    __syncthreads();

    // ---------------- Phase C: out-tile = f1 @ T (wave's 16 i1 rows) ----------
    bf16x8 bfrag[4];
#pragma unroll
    for (int kc = 0; kc < 4; ++kc) {   // K chunks of 32 (j1)
        unsigned int byte = (unsigned)(lm * 256 + (32 * kc + lk * 8) * 2);
        byte ^= (unsigned)((lm & 7) << 4);
        bfrag[kc] = *reinterpret_cast<const bf16x8*>(&Tt[byte]);
    }

    f32x4 acc2 = {0.f, 0.f, 0.f, 0.f};
#pragma unroll
    for (int kc = 0; kc < 4; ++kc) {
        const float4* pa = reinterpret_cast<const float4*>(
            f1 + (16 * w + lm) * 128 + 32 * kc + lk * 8);
        float4 a0 = pa[0], a1 = pa[1];
        bf16x8 af = pack8(a0, a1);
        acc2 = __builtin_amdgcn_mfma_f32_16x16x32_bf16(af, bfrag[kc], acc2, 0, 0, 0);
    }

    // Epilogue: out[b][i1 = 16w + lk*4 + r][i2 = 16q + lm] + bias
    const int i2 = 16 * q + lm;
#pragma unroll
    for (int r = 0; r < 4; ++r) {
        int i1 = 16 * w + lk * 4 + r;
        int col = i1 * 64 + i2;
        out[b * 8192 + col] = acc2[r] + bias[col];
    }
}

extern "C" void kernel_launch(void* const* d_in, const int* in_sizes, int n_in,
                              void* d_out, int out_size, void* d_ws, size_t ws_size,
                              hipStream_t stream) {
    (void)in_sizes; (void)n_in; (void)d_ws; (void)ws_size; (void)out_size;
    const float* x = (const float*)d_in[0];
    const float* f1 = (const float*)d_in[1];
    const float* f2 = (const float*)d_in[2];
    const float* bias = (const float*)d_in[3];
    float* out = (float*)d_out;

    kron_fused<<<256, 512, 0, stream>>>(x, f1, f2, bias, out);
}

// Round 3
// 10.907 us; speedup vs baseline: 1.9158x; 1.1353x over previous
//
#include <hip/hip_runtime.h>

// KroneckerLinear fused, bf16 MFMA, full software prefetch:
//   out[b, i1*64+i2] = bias[i1*64+i2]
//     + sum_j1 f1[i1,j1] * ( sum_j2 x[b, j1*64+j2] * f2[i2,j2] )
//
// Grid = 64 b * 4 i2-quarters (16 cols per block) -> T block-private, zero
// redundant FLOPs. Block = 512 thr = 8 waves; wave w owns j1-tile (phase B)
// and i1-tile (phase C).
//
// R3 change: ALL global loads (x, f2, f1, bias) issued at kernel entry so
// their ~900cy HBM-cold latencies overlap into one window (the compiler
// cannot hoist the f1/bias loads above __syncthreads itself). f1 packed to
// bf16 fragments BEFORE the barrier; post-barrier path is ds_read -> 4 MFMA
// -> store only.
//
// mfma_f32_16x16x32_bf16 layouts (m89-verified):
//   A: lane L holds A[L&15][(L>>4)*8 + i], i=0..7
//   B: lane L holds B[(L>>4)*8 + i][L&15]
//   C/D: lane L reg r -> (row=(L>>4)*4+r, col=L&15)

typedef __attribute__((ext_vector_type(8))) short bf16x8;
typedef __attribute__((ext_vector_type(4))) float f32x4;

static __device__ __forceinline__ unsigned short f2bf(float f) {
    unsigned int u = __builtin_bit_cast(unsigned int, f);
    u += 0x7FFFu + ((u >> 16) & 1u);   // RNE (inputs finite)
    return (unsigned short)(u >> 16);
}

static __device__ __forceinline__ bf16x8 pack8(float4 a, float4 b) {
    bf16x8 v;
    v[0] = (short)f2bf(a.x); v[1] = (short)f2bf(a.y);
    v[2] = (short)f2bf(a.z); v[3] = (short)f2bf(a.w);
    v[4] = (short)f2bf(b.x); v[5] = (short)f2bf(b.y);
    v[6] = (short)f2bf(b.z); v[7] = (short)f2bf(b.w);
    return v;
}

__global__ __launch_bounds__(512) void kron_fused(const float* __restrict__ x,
                                                  const float* __restrict__ f1,
                                                  const float* __restrict__ f2,
                                                  const float* __restrict__ bias,
                                                  float* __restrict__ out) {
    // Tt[i2'][j1] bf16: 16 x 128 x 2B = 4KB, rows 256B, XOR-swizzled
    // (byte ^= (i2'&7)<<4) so stride-256B column reads don't bank-conflict.
    __shared__ unsigned int TtU[16 * 64];
    unsigned char* Tt = reinterpret_cast<unsigned char*>(TtU);

    const int t = threadIdx.x;
    const int L = t & 63;
    const int w = t >> 6;              // wave 0..7
    const int b = blockIdx.x >> 2;
    const int q = blockIdx.x & 3;
    const int lm = L & 15;
    const int lk = L >> 4;

    // ---------------- Prefetch EVERYTHING ------------------------------------
    const float* xb = x + b * 8192;
    const float4* xp = reinterpret_cast<const float4*>(xb + (16 * w + lm) * 64 + lk * 8);
    const float4* f2p = reinterpret_cast<const float4*>(f2 + (16 * q + lm) * 64 + lk * 8);
    const float4* f1p = reinterpret_cast<const float4*>(f1 + (16 * w + lm) * 128 + lk * 8);

    float4 xa0 = xp[0], xa1 = xp[1];           // j2 chunk 0 (cols lk*8 .. +8)
    float4 xb0 = xp[8], xb1 = xp[9];           // j2 chunk 1 (cols 32+lk*8 ..)
    float4 fa0 = f2p[0], fa1 = f2p[1];
    float4 fb0 = f2p[8], fb1 = f2p[9];

    float4 f1r[4][2];
#pragma unroll
    for (int kc = 0; kc < 4; ++kc) {           // j1 chunks of 32
        f1r[kc][0] = f1p[kc * 8 + 0];
        f1r[kc][1] = f1p[kc * 8 + 1];
    }

    const int i2 = 16 * q + lm;
    float biasv[4];
#pragma unroll
    for (int r = 0; r < 4; ++r)
        biasv[r] = bias[(16 * w + lk * 4 + r) * 64 + i2];

    // ---------------- Phase B: T = Xb @ f2q^T --------------------------------
    f32x4 acc = {0.f, 0.f, 0.f, 0.f};
    acc = __builtin_amdgcn_mfma_f32_16x16x32_bf16(pack8(xa0, xa1), pack8(fa0, fa1), acc, 0, 0, 0);
    acc = __builtin_amdgcn_mfma_f32_16x16x32_bf16(pack8(xb0, xb1), pack8(fb0, fb1), acc, 0, 0, 0);

    // Pre-pack f1 A-fragments (keeps post-barrier path minimal).
    bf16x8 f1f[4];
#pragma unroll
    for (int kc = 0; kc < 4; ++kc) f1f[kc] = pack8(f1r[kc][0], f1r[kc][1]);

    // acc reg r = T[j1 = 16w + lk*4 + r][i2' = lm]; store transposed bf16,
    // Tt[lm][16w + lk*4 .. +4] = 8B contiguous, swizzled.
    {
        unsigned int lo = ((unsigned)f2bf(acc[1]) << 16) | f2bf(acc[0]);
        unsigned int hi = ((unsigned)f2bf(acc[3]) << 16) | f2bf(acc[2]);
        unsigned int byte = (unsigned)(lm * 256 + (16 * w + lk * 4) * 2);
        byte ^= (unsigned)((lm & 7) << 4);
        *reinterpret_cast<uint2*>(&Tt[byte]) = make_uint2(lo, hi);
    }
    __syncthreads();

    // ---------------- Phase C: out-tile = f1 @ T -----------------------------
    bf16x8 bfrag[4];
#pragma unroll
    for (int kc = 0; kc < 4; ++kc) {
        unsigned int byte = (unsigned)(lm * 256 + (32 * kc + lk * 8) * 2);
        byte ^= (unsigned)((lm & 7) << 4);
        bfrag[kc] = *reinterpret_cast<const bf16x8*>(&Tt[byte]);
    }

    f32x4 acc2 = {0.f, 0.f, 0.f, 0.f};
#pragma unroll
    for (int kc = 0; kc < 4; ++kc)
        acc2 = __builtin_amdgcn_mfma_f32_16x16x32_bf16(f1f[kc], bfrag[kc], acc2, 0, 0, 0);

    // Epilogue: out[b][i1 = 16w + lk*4 + r][i2] + bias (prefetched)
#pragma unroll
    for (int r = 0; r < 4; ++r) {
        int i1 = 16 * w + lk * 4 + r;
        out[b * 8192 + i1 * 64 + i2] = acc2[r] + biasv[r];
    }
}

extern "C" void kernel_launch(void* const* d_in, const int* in_sizes, int n_in,
                              void* d_out, int out_size, void* d_ws, size_t ws_size,
                              hipStream_t stream) {
    (void)in_sizes; (void)n_in; (void)d_ws; (void)ws_size; (void)out_size;
    const float* x = (const float*)d_in[0];
    const float* f1 = (const float*)d_in[1];
    const float* f2 = (const float*)d_in[2];
    const float* bias = (const float*)d_in[3];
    float* out = (float*)d_out;

    kron_fused<<<256, 512, 0, stream>>>(x, f1, f2, bias, out);
}